// Round 14
// baseline (382.921 us; speedup 1.0000x reference)
//
#include <hip/hip_runtime.h>
#include <math.h>

#define NN 100000
#define NE 1600000
#define FIN 64
#define HID 16
#define NC 40

#define NG 512      // dst-range buckets
#define GN 196      // nodes per bucket: 512*196 = 100352 >= NN
#define GCAP 3600   // records per bucket (mean 3125, sigma ~56, +8 sigma safe)
#define CH 4096     // edges per k_bucket block
#define NBK ((NE + CH - 1) / CH)  // 391
#define GB 64       // nodes per gather block
#define NGB ((NN + GB - 1) / GB) // 1563

typedef unsigned int u32;
typedef unsigned long long u64;
typedef unsigned short u16;
typedef unsigned char u8;

__device__ inline u16 f2bf(float f) {
    u32 u = __float_as_uint(f);
    return (u16)((u + 0x7FFF + ((u >> 16) & 1)) >> 16);  // RNE
}

// zero the 32 KB cursor array without the rocclr blit path
__global__ void k_zero(int* __restrict__ p) {
    p[blockIdx.x * 256 + threadIdx.x] = 0;
}

// ---- phase 1: bucket multi-split with in-LDS sort + coalesced run writes ----
// record: bits63..48 = g, 47..32 = local_d, 31..17 = ewq15, 16..0 = src
__global__ void __launch_bounds__(256) k_bucket(const int* __restrict__ src,
                                                const int* __restrict__ dst,
                                                const float* __restrict__ ew,
                                                int* __restrict__ bcur,
                                                u64* __restrict__ stg) {
    __shared__ u64 stage[CH];      // 32 KB
    __shared__ int lcnt[NG];
    __shared__ int loff[NG];
    __shared__ int lcur[NG];
    __shared__ int gst[NG];
    __shared__ int ssum[256];
    __shared__ int totsh;
    int tid = threadIdx.x;
    int e0 = blockIdx.x * CH;
    for (int i = tid; i < NG; i += 256) lcnt[i] = 0;
    __syncthreads();
    u32 hb[16];
    #pragma unroll
    for (int k = 0; k < 16; ++k) {
        int e = e0 + k * 256 + tid;
        hb[k] = 0xFFFFFFFFu;
        if (e < NE) {
            int d = dst[e];
            int g = d / GN;
            hb[k] = ((u32)g << 16) | (u32)(d - g * GN);
            atomicAdd(&lcnt[g], 1);
        }
    }
    __syncthreads();
    // scan 512 counts (2 per thread)
    int b0 = lcnt[2 * tid], b1c = lcnt[2 * tid + 1];
    int s = b0 + b1c;
    ssum[tid] = s;
    __syncthreads();
    #pragma unroll
    for (int off = 1; off < 256; off <<= 1) {
        int t = tid >= off ? ssum[tid - off] : 0;
        __syncthreads();
        ssum[tid] += t;
        __syncthreads();
    }
    int excl = ssum[tid] - s;
    loff[2 * tid] = excl;         loff[2 * tid + 1] = excl + b0;
    lcur[2 * tid] = excl;         lcur[2 * tid + 1] = excl + b0;
    gst[2 * tid]     = atomicAdd(&bcur[(2 * tid) << 4], b0);
    gst[2 * tid + 1] = atomicAdd(&bcur[(2 * tid + 1) << 4], b1c);
    if (tid == 255) totsh = ssum[255];
    __syncthreads();
    // stage records ordered by bucket
    #pragma unroll
    for (int k = 0; k < 16; ++k) {
        if (hb[k] != 0xFFFFFFFFu) {
            int e = e0 + k * 256 + tid;
            int g = hb[k] >> 16;
            u32 q = (u32)fminf(ew[e] * 32767.f + 0.5f, 32767.f);
            u32 lo = (u32)src[e] | (q << 17);
            int slot = atomicAdd(&lcur[g], 1);
            stage[slot] = ((u64)hb[k] << 32) | (u64)lo;
        }
    }
    __syncthreads();
    // coalesced write-out of per-bucket runs
    int total = totsh;
    for (int i = tid; i < total; i += 256) {
        u64 r = stage[i];
        int g = (int)(r >> 48);
        int slot = gst[g] + (i - loff[g]);
        if (slot < GCAP) stg[(size_t)g * GCAP + slot] = r;
    }
}

// ---- fused builder: hist + scans + row_ptr/dinv + placement, one block per bucket ----
__global__ void __launch_bounds__(256) k_build(const u64* __restrict__ stg,
                                               const int* __restrict__ bcur,
                                               int* __restrict__ row_ptr,
                                               float* __restrict__ dinv,
                                               u32* __restrict__ edges4,
                                               u8* __restrict__ dloc) {
    __shared__ u32 hc[GN];   // counts, then cursors
    __shared__ u32 hw[GN];   // fixed-point weighted degree
    __shared__ int tsum[256];
    __shared__ int sb[NG];   // bucket counts, then exclusive bucket prefix
    int g = blockIdx.x, tid = threadIdx.x;
    for (int i = tid; i < GN; i += 256) { hc[i] = 0; hw[i] = 0; }
    for (int i = tid; i < NG; i += 256) sb[i] = bcur[i << 4];
    __syncthreads();
    int n = sb[g];
    int b0 = sb[2 * tid], b1 = sb[2 * tid + 1];
    const u64* base = stg + (size_t)g * GCAP;
    // pass 1: per-node histogram via LDS atomics
    for (int i = tid; i < n; i += 256) {
        u64 r = base[i];
        int ld = (int)((r >> 32) & 0xFFFF);
        atomicAdd(&hc[ld], 1u);
        atomicAdd(&hw[ld], ((u32)r) >> 17);
    }
    __syncthreads();
    // bucket-prefix scan (512 counts, 2 per thread) -> sb = exclusive prefix
    int s2 = b0 + b1;
    tsum[tid] = s2;
    __syncthreads();
    #pragma unroll
    for (int off = 1; off < 256; off <<= 1) {
        int t = tid >= off ? tsum[tid - off] : 0;
        __syncthreads();
        tsum[tid] += t;
        __syncthreads();
    }
    int excl = tsum[tid] - s2;
    sb[2 * tid] = excl; sb[2 * tid + 1] = excl + b0;
    __syncthreads();
    int gbase = sb[g];
    // node-local scan (GN=196 <= 256, one per thread)
    int c = (tid < GN) ? (int)hc[tid] : 0;
    tsum[tid] = c;
    __syncthreads();
    #pragma unroll
    for (int off = 1; off < 256; off <<= 1) {
        int t = tid >= off ? tsum[tid - off] : 0;
        __syncthreads();
        tsum[tid] += t;
        __syncthreads();
    }
    if (tid < GN) {
        int run = gbase + tsum[tid] - c;
        int nd = g * GN + tid;
        if (nd <= NN) {
            row_ptr[nd] = run;
            if (nd < NN) {
                float deg = (float)hw[tid] * (1.0f / 32767.0f);
                dinv[nd] = deg > 0.f ? rsqrtf(fmaxf(deg, 1e-30f)) : 0.f;
            }
        }
        hc[tid] = (u32)run;  // cursor
    }
    __syncthreads();
    // pass 2: place 4B records + 1B local-node (within 64-node gather group)
    for (int i = tid; i < n; i += 256) {
        u64 r = base[i];
        int ld = (int)((r >> 32) & 0xFFFF);
        int pos = (int)atomicAdd(&hc[ld], 1u);
        edges4[pos] = (u32)r;
        dloc[pos] = (u8)((g * GN + ld) & 63);
    }
}

// ---- mm1: 2 threads per node. sel0 -> A1 row (f32), sel1 -> B0h row (bf16, *dinv) ----
__global__ void __launch_bounds__(256) k_mm1(const float* __restrict__ x,
                                             const float* __restrict__ W1,
                                             const float* __restrict__ dinv,
                                             float* __restrict__ A1,
                                             u16* __restrict__ B0h) {
    __shared__ float4 w4[512];
    int tid = threadIdx.x;
    for (int i = tid; i < 512; i += 256) w4[i] = *(const float4*)(W1 + i * 4);
    __syncthreads();
    int sel = tid >> 7;
    int node = blockIdx.x * 128 + (tid & 127);
    if (node >= NN) return;
    const float4* xr = (const float4*)(x + node * FIN);
    const float4* wb = w4 + sel * 256;
    float4 a0 = {0,0,0,0}, a1 = {0,0,0,0}, a2 = {0,0,0,0}, a3 = {0,0,0,0};
    #pragma unroll
    for (int ft = 0; ft < 16; ++ft) {
        float4 xv = xr[ft];
        const float4* wf = wb + ft * 16;
        #pragma unroll
        for (int q = 0; q < 4; ++q) {
            float xs = q == 0 ? xv.x : q == 1 ? xv.y : q == 2 ? xv.z : xv.w;
            float4 w0 = wf[q * 4 + 0], w1v = wf[q * 4 + 1], w2v = wf[q * 4 + 2], w3v = wf[q * 4 + 3];
            a0.x += xs * w0.x; a0.y += xs * w0.y; a0.z += xs * w0.z; a0.w += xs * w0.w;
            a1.x += xs * w1v.x; a1.y += xs * w1v.y; a1.z += xs * w1v.z; a1.w += xs * w1v.w;
            a2.x += xs * w2v.x; a2.y += xs * w2v.y; a2.z += xs * w2v.z; a2.w += xs * w2v.w;
            a3.x += xs * w3v.x; a3.y += xs * w3v.y; a3.z += xs * w3v.z; a3.w += xs * w3v.w;
        }
    }
    if (sel == 0) {
        float4* o = (float4*)(A1 + node * HID);
        o[0] = a0; o[1] = a1; o[2] = a2; o[3] = a3;
    } else {
        float di = dinv[node];
        uint4 p0, p1;
        p0.x = f2bf(a0.x * di) | ((u32)f2bf(a0.y * di) << 16);
        p0.y = f2bf(a0.z * di) | ((u32)f2bf(a0.w * di) << 16);
        p0.z = f2bf(a1.x * di) | ((u32)f2bf(a1.y * di) << 16);
        p0.w = f2bf(a1.z * di) | ((u32)f2bf(a1.w * di) << 16);
        p1.x = f2bf(a2.x * di) | ((u32)f2bf(a2.y * di) << 16);
        p1.y = f2bf(a2.z * di) | ((u32)f2bf(a2.w * di) << 16);
        p1.z = f2bf(a3.x * di) | ((u32)f2bf(a3.y * di) << 16);
        p1.w = f2bf(a3.z * di) | ((u32)f2bf(a3.w * di) << 16);
        uint4* o = (uint4*)(B0h + node * HID);
        o[0] = p0; o[1] = p1;
    }
}

// ---- block-centric gather: 64 nodes/block, edge-parallel, LDS f32 accumulate ----
// quantum i = (edge i>>3, u32-col q=i&7); coalesced edges4/dloc, 32B B-row runs.
// MODE 0: h = relu(A1 - dinv*acc + b1) -> o1 f32; o2 = bf16(h*dinv)
// MODE 1: Th = -dinv*acc -> o1 f32
template <int MODE>
__global__ void __launch_bounds__(256) k_gather(const int* __restrict__ row_ptr,
                                                const u32* __restrict__ edges4,
                                                const u8* __restrict__ dloc,
                                                const u16* __restrict__ Bh,
                                                const float* __restrict__ A1,
                                                const float* __restrict__ b1,
                                                const float* __restrict__ dinv,
                                                float* __restrict__ o1,
                                                u16* __restrict__ o2) {
    __shared__ float acc[GB * HID];  // 4 KB
    int tid = threadIdx.x;
    int n0 = blockIdx.x * GB;
    #pragma unroll
    for (int i = tid; i < GB * HID; i += 256) acc[i] = 0.f;
    __syncthreads();
    int nend = n0 + GB; if (nend > NN) nend = NN;
    int beg = row_ptr[n0], end = row_ptr[nend];
    const u32* Bw = (const u32*)Bh;
    int total = (end - beg) << 3;
    for (int i = tid; i < total; i += 256) {
        int e = beg + (i >> 3);
        int q = i & 7;
        u32 rec = edges4[e];
        u32 c = Bw[(rec & 0x1FFFF) * 8 + q];
        float w = (float)(rec >> 17);
        int dl = (int)dloc[e];
        atomicAdd(&acc[dl * HID + 2 * q],     w * __uint_as_float(c << 16));
        atomicAdd(&acc[dl * HID + 2 * q + 1], w * __uint_as_float(c & 0xFFFF0000u));
    }
    __syncthreads();
    // epilogue: 512 (node, col-pair) quanta
    for (int idx = tid; idx < GB * 8; idx += 256) {
        int ln = idx >> 3, q = idx & 7;
        int nd = n0 + ln;
        if (nd >= NN) continue;
        float di = dinv[nd];
        float sc = di * (1.0f / 32767.0f);
        float aL = acc[ln * HID + 2 * q];
        float aH = acc[ln * HID + 2 * q + 1];
        int f = 2 * q;
        if (MODE == 0) {
            float2 a = *(const float2*)(A1 + nd * HID + f);
            float2 bb = *(const float2*)(b1 + f);
            float hL = fmaxf(a.x - sc * aL + bb.x, 0.f);
            float hH = fmaxf(a.y - sc * aH + bb.y, 0.f);
            *(float2*)(o1 + nd * HID + f) = make_float2(hL, hH);
            ((u32*)o2)[nd * 8 + q] = (u32)f2bf(hL * di) | ((u32)f2bf(hH * di) << 16);
        } else {
            *(float2*)(o1 + nd * HID + f) = make_float2(-sc * aL, -sc * aH);
        }
    }
}

// thread-per-node: logits in regs, W2 broadcast from LDS, native exp/log
__global__ void __launch_bounds__(256) k_mm2_lsm(const float* __restrict__ h,
                                                 const float* __restrict__ Th,
                                                 const float* __restrict__ W2,
                                                 const float* __restrict__ b2,
                                                 float* __restrict__ out) {
    __shared__ float4 w4[32][10];
    __shared__ float sb2[NC];
    int tid = threadIdx.x;
    for (int i = tid; i < 320; i += 256) {
        int f = i / 10, ct = i % 10;
        w4[f][ct] = *(const float4*)(W2 + f * 40 + ct * 4);
    }
    for (int i = tid; i < NC; i += 256) sb2[i] = b2[i];
    __syncthreads();
    int node = blockIdx.x * 256 + tid;
    if (node >= NN) return;
    float v[32];
    const float4* hp = (const float4*)(h + node * HID);
    const float4* tp = (const float4*)(Th + node * HID);
    #pragma unroll
    for (int q = 0; q < 4; ++q) {
        float4 a = hp[q];
        v[4 * q + 0] = a.x; v[4 * q + 1] = a.y; v[4 * q + 2] = a.z; v[4 * q + 3] = a.w;
        float4 b = tp[q];
        v[16 + 4 * q + 0] = b.x; v[16 + 4 * q + 1] = b.y; v[16 + 4 * q + 2] = b.z; v[16 + 4 * q + 3] = b.w;
    }
    float lg[NC];
    #pragma unroll
    for (int ct = 0; ct < 10; ++ct) {
        float ax = sb2[ct * 4 + 0], ay = sb2[ct * 4 + 1], az = sb2[ct * 4 + 2], aw = sb2[ct * 4 + 3];
        #pragma unroll
        for (int f = 0; f < 32; ++f) {
            float4 wv = w4[f][ct];
            ax += v[f] * wv.x; ay += v[f] * wv.y; az += v[f] * wv.z; aw += v[f] * wv.w;
        }
        lg[ct * 4 + 0] = ax; lg[ct * 4 + 1] = ay; lg[ct * 4 + 2] = az; lg[ct * 4 + 3] = aw;
    }
    float m = lg[0];
    #pragma unroll
    for (int c = 1; c < NC; ++c) m = fmaxf(m, lg[c]);
    float sum = 0.f;
    #pragma unroll
    for (int c = 0; c < NC; ++c) sum += __expf(lg[c] - m);
    float lse = m + __logf(sum);
    float* orow = out + node * NC;
    #pragma unroll
    for (int ct = 0; ct < 10; ++ct) {
        float4 r;
        r.x = lg[ct * 4 + 0] - lse; r.y = lg[ct * 4 + 1] - lse;
        r.z = lg[ct * 4 + 2] - lse; r.w = lg[ct * 4 + 3] - lse;
        *(float4*)(orow + ct * 4) = r;
    }
}

extern "C" void kernel_launch(void* const* d_in, const int* in_sizes, int n_in,
                              void* d_out, int out_size, void* d_ws, size_t ws_size,
                              hipStream_t stream) {
    const float* x  = (const float*)d_in[0];
    const float* ew = (const float*)d_in[1];
    const float* W1 = (const float*)d_in[2];
    const float* b1 = (const float*)d_in[3];
    const float* W2 = (const float*)d_in[4];
    const float* b2 = (const float*)d_in[5];
    const int*   ei = (const int*)d_in[6];
    const int* src = ei;
    const int* dst = ei + NE;
    float* out = (float*)d_out;

    const int NPAD = 100352;  // = NG*GN
    int*   bcur    = (int*)d_ws;                       // NG*16 ints (spread cursors)
    u64*   stg     = (u64*)(bcur + NG * 16);           // NG*GCAP u64 (~14.7MB)
    u32*   edges4  = (u32*)(stg + (size_t)NG * GCAP);  // NE u32 (6.4MB)
    int*   row_ptr = (int*)(edges4 + NE);              // NPAD i (uses NN+1)
    float* dinv    = (float*)(row_ptr + NPAD);         // NPAD f
    float* A1      = dinv + NPAD;                      // NN*HID f
    float* h       = A1 + NN * HID;                    // NN*HID f
    float* Th      = h + NN * HID;                     // NN*HID f
    u16*   B0h     = (u16*)(Th + NN * HID);            // NN*HID u16 (3.2MB)
    u16*   h2      = B0h + NN * HID;                   // NN*HID u16 (3.2MB)
    u8*    dloc    = (u8*)(h2 + NN * HID);             // NE u8 (1.6MB)

    k_zero<<<NG * 16 / 256, 256, 0, stream>>>(bcur);
    k_bucket<<<NBK, 256, 0, stream>>>(src, dst, ew, bcur, stg);
    k_build<<<NG, 256, 0, stream>>>(stg, bcur, row_ptr, dinv, edges4, dloc);
    k_mm1<<<(NN + 127) / 128, 256, 0, stream>>>(x, W1, dinv, A1, B0h);
    k_gather<0><<<NGB, 256, 0, stream>>>(row_ptr, edges4, dloc, B0h, A1, b1, dinv, h, h2);
    k_gather<1><<<NGB, 256, 0, stream>>>(row_ptr, edges4, dloc, h2, nullptr, nullptr, dinv, Th, nullptr);
    k_mm2_lsm<<<(NN + 255) / 256, 256, 0, stream>>>(h, Th, W2, b2, out);
}

// Round 15
// 131.446 us; speedup vs baseline: 2.9131x; 2.9131x over previous
//
#include <hip/hip_runtime.h>
#include <math.h>

#define NN 100000
#define NE 1600000
#define FIN 64
#define HID 16
#define NC 40

#define NG 512      // dst-range buckets
#define GN 196      // nodes per bucket: 512*196 = 100352 >= NN
#define GCAP 3600   // records per bucket (mean 3125, sigma ~56, +8 sigma safe)
#define CH 4096     // edges per k_bucket block
#define NBK ((NE + CH - 1) / CH)  // 391

typedef unsigned int u32;
typedef unsigned long long u64;
typedef unsigned short u16;

__device__ inline u16 f2bf(float f) {
    u32 u = __float_as_uint(f);
    return (u16)((u + 0x7FFF + ((u >> 16) & 1)) >> 16);  // RNE
}

// zero the 32 KB cursor array without the rocclr blit path
__global__ void k_zero(int* __restrict__ p) {
    p[blockIdx.x * 256 + threadIdx.x] = 0;
}

// ---- phase 1: bucket multi-split with in-LDS sort + coalesced run writes ----
// record: bits63..48 = g, 47..32 = local_d, 31..17 = ewq15, 16..0 = src
__global__ void __launch_bounds__(256) k_bucket(const int* __restrict__ src,
                                                const int* __restrict__ dst,
                                                const float* __restrict__ ew,
                                                int* __restrict__ bcur,
                                                u64* __restrict__ stg) {
    __shared__ u64 stage[CH];      // 32 KB
    __shared__ int lcnt[NG];
    __shared__ int loff[NG];
    __shared__ int lcur[NG];
    __shared__ int gst[NG];
    __shared__ int ssum[256];
    __shared__ int totsh;
    int tid = threadIdx.x;
    int e0 = blockIdx.x * CH;
    for (int i = tid; i < NG; i += 256) lcnt[i] = 0;
    __syncthreads();
    u32 hb[16];
    #pragma unroll
    for (int k = 0; k < 16; ++k) {
        int e = e0 + k * 256 + tid;
        hb[k] = 0xFFFFFFFFu;
        if (e < NE) {
            int d = dst[e];
            int g = d / GN;
            hb[k] = ((u32)g << 16) | (u32)(d - g * GN);
            atomicAdd(&lcnt[g], 1);
        }
    }
    __syncthreads();
    // scan 512 counts (2 per thread)
    int b0 = lcnt[2 * tid], b1c = lcnt[2 * tid + 1];
    int s = b0 + b1c;
    ssum[tid] = s;
    __syncthreads();
    #pragma unroll
    for (int off = 1; off < 256; off <<= 1) {
        int t = tid >= off ? ssum[tid - off] : 0;
        __syncthreads();
        ssum[tid] += t;
        __syncthreads();
    }
    int excl = ssum[tid] - s;
    loff[2 * tid] = excl;         loff[2 * tid + 1] = excl + b0;
    lcur[2 * tid] = excl;         lcur[2 * tid + 1] = excl + b0;
    gst[2 * tid]     = atomicAdd(&bcur[(2 * tid) << 4], b0);
    gst[2 * tid + 1] = atomicAdd(&bcur[(2 * tid + 1) << 4], b1c);
    if (tid == 255) totsh = ssum[255];
    __syncthreads();
    // stage records ordered by bucket
    #pragma unroll
    for (int k = 0; k < 16; ++k) {
        if (hb[k] != 0xFFFFFFFFu) {
            int e = e0 + k * 256 + tid;
            int g = hb[k] >> 16;
            u32 q = (u32)fminf(ew[e] * 32767.f + 0.5f, 32767.f);
            u32 lo = (u32)src[e] | (q << 17);
            int slot = atomicAdd(&lcur[g], 1);
            stage[slot] = ((u64)hb[k] << 32) | (u64)lo;
        }
    }
    __syncthreads();
    // coalesced write-out of per-bucket runs
    int total = totsh;
    for (int i = tid; i < total; i += 256) {
        u64 r = stage[i];
        int g = (int)(r >> 48);
        int slot = gst[g] + (i - loff[g]);
        if (slot < GCAP) stg[(size_t)g * GCAP + slot] = r;
    }
}

// ---- fused builder: LDS-staged records, hist + scans + row_ptr/dinv + placement ----
__global__ void __launch_bounds__(256) k_build(const u64* __restrict__ stg,
                                               const int* __restrict__ bcur,
                                               int* __restrict__ row_ptr,
                                               float* __restrict__ dinv,
                                               u32* __restrict__ edges4) {
    __shared__ u64 lrec[GCAP];  // 28.8 KB: bucket records, read from global ONCE
    __shared__ u32 hc[GN];      // counts, then cursors
    __shared__ u32 hw[GN];      // fixed-point weighted degree
    __shared__ int tsum[256];
    __shared__ int sb[NG];      // bucket counts, then exclusive bucket prefix
    int g = blockIdx.x, tid = threadIdx.x;
    for (int i = tid; i < GN; i += 256) { hc[i] = 0; hw[i] = 0; }
    for (int i = tid; i < NG; i += 256) sb[i] = bcur[i << 4];
    __syncthreads();
    int n = sb[g];
    if (n > GCAP) n = GCAP;
    int b0 = sb[2 * tid], b1 = sb[2 * tid + 1];
    const u64* base = stg + (size_t)g * GCAP;
    // pass 1: load to LDS + per-node histogram via LDS atomics
    for (int i = tid; i < n; i += 256) {
        u64 r = base[i];
        lrec[i] = r;
        int ld = (int)((r >> 32) & 0xFFFF);
        atomicAdd(&hc[ld], 1u);
        atomicAdd(&hw[ld], ((u32)r) >> 17);
    }
    __syncthreads();
    // bucket-prefix scan (512 counts, 2 per thread) -> sb = exclusive prefix
    int s2 = b0 + b1;
    tsum[tid] = s2;
    __syncthreads();
    #pragma unroll
    for (int off = 1; off < 256; off <<= 1) {
        int t = tid >= off ? tsum[tid - off] : 0;
        __syncthreads();
        tsum[tid] += t;
        __syncthreads();
    }
    int excl = tsum[tid] - s2;
    sb[2 * tid] = excl; sb[2 * tid + 1] = excl + b0;
    __syncthreads();
    int gbase = sb[g];
    // node-local scan (GN=196 <= 256, one per thread)
    int c = (tid < GN) ? (int)hc[tid] : 0;
    tsum[tid] = c;
    __syncthreads();
    #pragma unroll
    for (int off = 1; off < 256; off <<= 1) {
        int t = tid >= off ? tsum[tid - off] : 0;
        __syncthreads();
        tsum[tid] += t;
        __syncthreads();
    }
    if (tid < GN) {
        int run = gbase + tsum[tid] - c;
        int nd = g * GN + tid;
        if (nd <= NN) {
            row_ptr[nd] = run;
            if (nd < NN) {
                float deg = (float)hw[tid] * (1.0f / 32767.0f);
                dinv[nd] = deg > 0.f ? rsqrtf(fmaxf(deg, 1e-30f)) : 0.f;
            }
        }
        hc[tid] = (u32)run;  // cursor
    }
    __syncthreads();
    // pass 2: place 4B records from LDS via LDS cursors
    for (int i = tid; i < n; i += 256) {
        u64 r = lrec[i];
        int ld = (int)((r >> 32) & 0xFFFF);
        edges4[atomicAdd(&hc[ld], 1u)] = (u32)r;
    }
}

// ---- mm1: 2 threads per node. sel0 -> A1 row (f32), sel1 -> B0h row (bf16, *dinv) ----
__global__ void __launch_bounds__(256) k_mm1(const float* __restrict__ x,
                                             const float* __restrict__ W1,
                                             const float* __restrict__ dinv,
                                             float* __restrict__ A1,
                                             u16* __restrict__ B0h) {
    __shared__ float4 w4[512];
    int tid = threadIdx.x;
    for (int i = tid; i < 512; i += 256) w4[i] = *(const float4*)(W1 + i * 4);
    __syncthreads();
    int sel = tid >> 7;
    int node = blockIdx.x * 128 + (tid & 127);
    if (node >= NN) return;
    const float4* xr = (const float4*)(x + node * FIN);
    const float4* wb = w4 + sel * 256;
    float4 a0 = {0,0,0,0}, a1 = {0,0,0,0}, a2 = {0,0,0,0}, a3 = {0,0,0,0};
    #pragma unroll
    for (int ft = 0; ft < 16; ++ft) {
        float4 xv = xr[ft];
        const float4* wf = wb + ft * 16;
        #pragma unroll
        for (int q = 0; q < 4; ++q) {
            float xs = q == 0 ? xv.x : q == 1 ? xv.y : q == 2 ? xv.z : xv.w;
            float4 w0 = wf[q * 4 + 0], w1v = wf[q * 4 + 1], w2v = wf[q * 4 + 2], w3v = wf[q * 4 + 3];
            a0.x += xs * w0.x; a0.y += xs * w0.y; a0.z += xs * w0.z; a0.w += xs * w0.w;
            a1.x += xs * w1v.x; a1.y += xs * w1v.y; a1.z += xs * w1v.z; a1.w += xs * w1v.w;
            a2.x += xs * w2v.x; a2.y += xs * w2v.y; a2.z += xs * w2v.z; a2.w += xs * w2v.w;
            a3.x += xs * w3v.x; a3.y += xs * w3v.y; a3.z += xs * w3v.z; a3.w += xs * w3v.w;
        }
    }
    if (sel == 0) {
        float4* o = (float4*)(A1 + node * HID);
        o[0] = a0; o[1] = a1; o[2] = a2; o[3] = a3;
    } else {
        float di = dinv[node];
        uint4 p0, p1;
        p0.x = f2bf(a0.x * di) | ((u32)f2bf(a0.y * di) << 16);
        p0.y = f2bf(a0.z * di) | ((u32)f2bf(a0.w * di) << 16);
        p0.z = f2bf(a1.x * di) | ((u32)f2bf(a1.y * di) << 16);
        p0.w = f2bf(a1.z * di) | ((u32)f2bf(a1.w * di) << 16);
        p1.x = f2bf(a2.x * di) | ((u32)f2bf(a2.y * di) << 16);
        p1.y = f2bf(a2.z * di) | ((u32)f2bf(a2.w * di) << 16);
        p1.z = f2bf(a3.x * di) | ((u32)f2bf(a3.y * di) << 16);
        p1.w = f2bf(a3.z * di) | ((u32)f2bf(a3.w * di) << 16);
        uint4* o = (uint4*)(B0h + node * HID);
        o[0] = p0; o[1] = p1;
    }
}

// wave per node, 8 edge-slots x 8 lanes, 2 packed bf16 features per lane. (r13 form)
// MODE 0: h = relu(A1 - dinv*acc + b1) -> o1 f32; o2 = bf16(h*dinv)
// MODE 1: Th = -dinv*acc -> o1 f32
template <int MODE>
__global__ void k_gather(const int* __restrict__ row_ptr, const u32* __restrict__ edges4,
                         const u16* __restrict__ Bh,
                         const float* __restrict__ A1, const float* __restrict__ b1,
                         const float* __restrict__ dinv,
                         float* __restrict__ o1, u16* __restrict__ o2) {
    int node = blockIdx.x * 4 + (threadIdx.x >> 6);
    int lane = threadIdx.x & 63;
    int slot = lane >> 3, q = lane & 7;   // 8 slots x 8 u32-columns
    if (node >= NN) return;
    int beg = row_ptr[node], end = row_ptr[node + 1];
    const u32* Bw = (const u32*)Bh;       // row = 8 u32 (16 bf16)
    float accL = 0.f, accH = 0.f;
    int p0 = beg + slot;
    if (end - beg <= 16) {
        u32 r0 = (p0 < end) ? edges4[p0] : 0u;       // rec 0 -> w=0, row 0 (hot)
        u32 r1 = (p0 + 8 < end) ? edges4[p0 + 8] : 0u;
        u32 c0 = Bw[(r0 & 0x1FFFF) * 8 + q];
        u32 c1 = Bw[(r1 & 0x1FFFF) * 8 + q];
        float w0 = (float)(r0 >> 17), w1 = (float)(r1 >> 17);
        accL = w0 * __uint_as_float(c0 << 16) + w1 * __uint_as_float(c1 << 16);
        accH = w0 * __uint_as_float(c0 & 0xFFFF0000u) + w1 * __uint_as_float(c1 & 0xFFFF0000u);
    } else {
        u32 r[4];
        #pragma unroll
        for (int k = 0; k < 4; ++k) {
            int p = p0 + 8 * k;
            r[k] = (p < end) ? edges4[p] : 0u;
        }
        #pragma unroll
        for (int k = 0; k < 4; ++k) {
            u32 c = Bw[(r[k] & 0x1FFFF) * 8 + q];
            float w = (float)(r[k] >> 17);
            accL += w * __uint_as_float(c << 16);
            accH += w * __uint_as_float(c & 0xFFFF0000u);
        }
        for (int p = p0 + 32; p < end; p += 8) {  // deg>32: rare
            u32 rr = edges4[p];
            u32 c = Bw[(rr & 0x1FFFF) * 8 + q];
            float w = (float)(rr >> 17);
            accL += w * __uint_as_float(c << 16);
            accH += w * __uint_as_float(c & 0xFFFF0000u);
        }
    }
    // reduce across the 8 slots
    #pragma unroll
    for (int m = 8; m < 64; m <<= 1) {
        accL += __shfl_xor(accL, m, 64);
        accH += __shfl_xor(accH, m, 64);
    }
    if (slot == 0) {
        float di = dinv[node];
        float sc = di * (1.0f / 32767.0f);
        int f = 2 * q;
        if (MODE == 0) {
            float2 a = *(const float2*)(A1 + node * HID + f);
            float2 bb = *(const float2*)(b1 + f);
            float hL = fmaxf(a.x - sc * accL + bb.x, 0.f);
            float hH = fmaxf(a.y - sc * accH + bb.y, 0.f);
            *(float2*)(o1 + node * HID + f) = make_float2(hL, hH);
            ((u32*)o2)[node * 8 + q] = (u32)f2bf(hL * di) | ((u32)f2bf(hH * di) << 16);
        } else {
            *(float2*)(o1 + node * HID + f) = make_float2(-sc * accL, -sc * accH);
        }
    }
}

// thread-per-node: logits in regs, W2 broadcast from LDS, native exp/log
__global__ void __launch_bounds__(256) k_mm2_lsm(const float* __restrict__ h,
                                                 const float* __restrict__ Th,
                                                 const float* __restrict__ W2,
                                                 const float* __restrict__ b2,
                                                 float* __restrict__ out) {
    __shared__ float4 w4[32][10];
    __shared__ float sb2[NC];
    int tid = threadIdx.x;
    for (int i = tid; i < 320; i += 256) {
        int f = i / 10, ct = i % 10;
        w4[f][ct] = *(const float4*)(W2 + f * 40 + ct * 4);
    }
    for (int i = tid; i < NC; i += 256) sb2[i] = b2[i];
    __syncthreads();
    int node = blockIdx.x * 256 + tid;
    if (node >= NN) return;
    float v[32];
    const float4* hp = (const float4*)(h + node * HID);
    const float4* tp = (const float4*)(Th + node * HID);
    #pragma unroll
    for (int q = 0; q < 4; ++q) {
        float4 a = hp[q];
        v[4 * q + 0] = a.x; v[4 * q + 1] = a.y; v[4 * q + 2] = a.z; v[4 * q + 3] = a.w;
        float4 b = tp[q];
        v[16 + 4 * q + 0] = b.x; v[16 + 4 * q + 1] = b.y; v[16 + 4 * q + 2] = b.z; v[16 + 4 * q + 3] = b.w;
    }
    float lg[NC];
    #pragma unroll
    for (int ct = 0; ct < 10; ++ct) {
        float ax = sb2[ct * 4 + 0], ay = sb2[ct * 4 + 1], az = sb2[ct * 4 + 2], aw = sb2[ct * 4 + 3];
        #pragma unroll
        for (int f = 0; f < 32; ++f) {
            float4 wv = w4[f][ct];
            ax += v[f] * wv.x; ay += v[f] * wv.y; az += v[f] * wv.z; aw += v[f] * wv.w;
        }
        lg[ct * 4 + 0] = ax; lg[ct * 4 + 1] = ay; lg[ct * 4 + 2] = az; lg[ct * 4 + 3] = aw;
    }
    float m = lg[0];
    #pragma unroll
    for (int c = 1; c < NC; ++c) m = fmaxf(m, lg[c]);
    float sum = 0.f;
    #pragma unroll
    for (int c = 0; c < NC; ++c) sum += __expf(lg[c] - m);
    float lse = m + __logf(sum);
    float* orow = out + node * NC;
    #pragma unroll
    for (int ct = 0; ct < 10; ++ct) {
        float4 r;
        r.x = lg[ct * 4 + 0] - lse; r.y = lg[ct * 4 + 1] - lse;
        r.z = lg[ct * 4 + 2] - lse; r.w = lg[ct * 4 + 3] - lse;
        *(float4*)(orow + ct * 4) = r;
    }
}

extern "C" void kernel_launch(void* const* d_in, const int* in_sizes, int n_in,
                              void* d_out, int out_size, void* d_ws, size_t ws_size,
                              hipStream_t stream) {
    const float* x  = (const float*)d_in[0];
    const float* ew = (const float*)d_in[1];
    const float* W1 = (const float*)d_in[2];
    const float* b1 = (const float*)d_in[3];
    const float* W2 = (const float*)d_in[4];
    const float* b2 = (const float*)d_in[5];
    const int*   ei = (const int*)d_in[6];
    const int* src = ei;
    const int* dst = ei + NE;
    float* out = (float*)d_out;

    const int NPAD = 100352;  // = NG*GN
    int*   bcur    = (int*)d_ws;                       // NG*16 ints (spread cursors)
    u64*   stg     = (u64*)(bcur + NG * 16);           // NG*GCAP u64 (~14.7MB)
    u32*   edges4  = (u32*)(stg + (size_t)NG * GCAP);  // NE u32 (6.4MB)
    int*   row_ptr = (int*)(edges4 + NE);              // NPAD i (uses NN+1)
    float* dinv    = (float*)(row_ptr + NPAD);         // NPAD f
    float* A1      = dinv + NPAD;                      // NN*HID f
    float* h       = A1 + NN * HID;                    // NN*HID f
    float* Th      = h + NN * HID;                     // NN*HID f
    u16*   B0h     = (u16*)(Th + NN * HID);            // NN*HID u16 (3.2MB)
    u16*   h2      = B0h + NN * HID;                   // NN*HID u16 (3.2MB)

    k_zero<<<NG * 16 / 256, 256, 0, stream>>>(bcur);
    k_bucket<<<NBK, 256, 0, stream>>>(src, dst, ew, bcur, stg);
    k_build<<<NG, 256, 0, stream>>>(stg, bcur, row_ptr, dinv, edges4);
    k_mm1<<<(NN + 127) / 128, 256, 0, stream>>>(x, W1, dinv, A1, B0h);
    k_gather<0><<<(NN + 3) / 4, 256, 0, stream>>>(row_ptr, edges4, B0h, A1, b1, dinv, h, h2);
    k_gather<1><<<(NN + 3) / 4, 256, 0, stream>>>(row_ptr, edges4, h2, nullptr, nullptr, dinv, Th, nullptr);
    k_mm2_lsm<<<(NN + 255) / 256, 256, 0, stream>>>(h, Th, W2, b2, out);
}